// Round 8
// baseline (273.977 us; speedup 1.0000x reference)
//
#include <hip/hip_runtime.h>

// DualModel3 R13: barrier-FREE K-loop — wave-private B staging.
// R5-R12: eight structural variants, all 84-122us, all pipes <15%. Falsified:
// occupancy (R6,R12), GLDS (R8), block count (R9), W1 burst shape (R10),
// barrier count (R12). Shared invariant: every K-step ends in a block-wide
// barrier, so waves walk the latency chain (vmem->cvt->ds_write->lgkm->
// barrier->ds_read->MFMA) in lockstep, with only ~2 barrier groups/CU to
// interleave. R13 removes the barrier's reason to exist: each WAVE stages its
// own private B-subtile into its own 8KB LDS region and reads only that.
// Zero s_barrier / zero waitcnt asm in the K-loop; compiler emits counted
// vmcnt/lgkmcnt per wave; 12 independent wave-pipelines/CU hide latency.
// Cost: 4 waves/block duplicate the W1 read -> 4x L2 traffic (536MB total,
// well under the 34.5TB/s ceiling; HBM unchanged, same lines L2-absorbed).
// Step = BK=32: 4 MFMA + 2 ds_read_b128 + 4 ds_write_b64 + 8 glb loads.
// B prefetch 2 steps ahead; A 1 step (L2-resident frag image).
// Byte-identical to R11 (twice-verified): pack_a frag-major image, bslot
// swizzle, MFMA g=2ks+half mapping, C/D col=lane&31 row=(r&3)+8*(r>>2)+4*half,
// epilogues, XCD swizzle 544=8x68, A replicas by XCD-pair.

typedef __bf16 bf16_t;
typedef __bf16 bf16x4v __attribute__((ext_vector_type(4)));
typedef __bf16 bf16x8 __attribute__((ext_vector_type(8)));
typedef float  f32x4  __attribute__((ext_vector_type(4)));
typedef float  f32x16 __attribute__((ext_vector_type(16)));

#define WS_REP_BYTES (1 << 20)     // 1 MB per A replica, 4 replicas

__device__ __forceinline__ int bslot(int n, int g) {
    return g ^ (n & 7) ^ (((n >> 3) & 3) << 1);
}

// ---------------------------------------------------------------- pass 1 ----
// (byte-identical to R11/R12 — verified) Frag-major A image:
// byte = rep*1MB + kt*32768 + (mchunk*256 + g*32 + lane31)*16;
// slot holds x[mchunk*32 + l][kt*64 + g*8 .. +7] as bf16x8.
__global__ __launch_bounds__(256)
void pack_a(const float* __restrict__ x, char* __restrict__ ws)
{
    const int kt  = blockIdx.x & 31;
    const int rep = blockIdx.x >> 5;                  // 0..3
    char* dst = ws + (size_t)rep * WS_REP_BYTES + (size_t)kt * 32768;
    const int tid = threadIdx.x;
    #pragma unroll
    for (int ii = 0; ii < 8; ++ii) {
        const int gi  = tid + 256 * ii;               // 0..2047
        const int mr5 = gi >> 8, g = (gi >> 5) & 7, l = gi & 31;
        const float* sp = x + (size_t)(mr5 * 32 + l) * 2048 + kt * 64 + g * 8;
        f32x4 v0 = *(const f32x4*)sp, v1 = *(const f32x4*)(sp + 4);
        bf16x8 o;
        #pragma unroll
        for (int c = 0; c < 4; ++c) { o[c] = (bf16_t)v0[c]; o[4 + c] = (bf16_t)v1[c]; }
        *(bf16x8*)(dst + gi * 16) = o;
    }
}

// ---------------------------------------------------------------- pass 2 ----
__global__ __launch_bounds__(256, 3)    // VGPR cap 170 (est ~140); 32KB LDS -> 3 blk/CU
void fused_dual(const char* __restrict__ ws,
                const float* __restrict__ W1,   // [4096,2048,4] fp32
                const float* __restrict__ fcW,  // [1000,2048] fp32
                const float* __restrict__ fcb,
                const float* __restrict__ b1,
                const float* __restrict__ W2,
                const float* __restrict__ b2,
                float* __restrict__ out)        // x1[256*1000] ++ x2[256*4096]
{
    __shared__ __align__(16) char lds[4][8192];   // per-WAVE: 2 bufs x 4KB

    const int tid  = threadIdx.x;
    const int lane = tid & 63, w = tid >> 6;      // 4 waves
    const int l31  = lane & 31, half = lane >> 5;

    // XCD swizzle: 544 = 8 x 68, bijective (R11-verified).
    const int idx = blockIdx.x;
    const int wid = (idx & 7) * 68 + (idx >> 3);
    const bool is_fc = (wid >= 512);
    const int d   = wid;                 // decoder block: o in [d*8, +8)
    const int fcI = wid - 512;           // fc block: cols [fcI*32, +32)

    const char* aRep = ws + (size_t)((idx & 7) >> 1) * WS_REP_BYTES;
    char* myLds = lds[w];

    // A-frag constants: frag(i,ksl) byte = kt*32768 + ph*2048 + (2w+i)*4096
    //                                     + ksl*1024 + half*512 + l31*16
    const int aA0 = (2 * w) * 4096 + half * 512 + l31 * 16;

    // B-frag read offsets (step parity ph flips byte bit 6: slot g -> g^4)
    const int bro0 = l31 * 128 + bslot(l31, half) * 16;       // ksl=0 (g=half)
    const int bro1 = l31 * 128 + bslot(l31, 2 + half) * 16;   // ksl=1 (g=2+half)

    // ---- per-lane B staging map (each wave stages its FULL 32n x 32k step) --
    const float* bSrc; int bStep;
    int dwo0 = 0, dwo1 = 0, dwo2 = 0, dwo3 = 0, fco0 = 0, fco1 = 0;
    if (is_fc) {
        // lane: n = lane>>1 (c-row), kh = lane&1 (16-k half). 16 consec floats.
        const int n = lane >> 1, kh = lane & 1;
        int c = fcI * 32 + n; if (c > 999) c = 999;   // stores guarded
        bSrc = fcW + (size_t)c * 2048 + kh * 16;
        bStep = 32;                                    // floats per step
        fco0 = n * 128 + bslot(n, kh * 2) * 16;        // ph=0 slots; ^64 for ph=1
        fco1 = n * 128 + bslot(n, kh * 2 + 1) * 16;
    } else {
        // lane: o = lane>>3, sub = lane&7 -> W1[o][k0+sub*4 .. +3][0..3],
        // 16 consec floats. Writes: per h, row n=4o+h, g=sub>>1, 8B-half=sub&1.
        const int o = lane >> 3, sub = lane & 7;
        bSrc = W1 + (size_t)(d * 8 + o) * 8192 + sub * 16;
        bStep = 128;
        const int g0 = sub >> 1, h8 = (sub & 1) * 8;
        dwo0 = (4 * o + 0) * 128 + bslot(4 * o + 0, g0) * 16 + h8;
        dwo1 = (4 * o + 1) * 128 + bslot(4 * o + 1, g0) * 16 + h8;
        dwo2 = (4 * o + 2) * 128 + bslot(4 * o + 2, g0) * 16 + h8;
        dwo3 = (4 * o + 3) * 128 + bslot(4 * o + 3, g0) * 16 + h8;
    }

    f32x16 acc[2];
    #pragma unroll
    for (int i = 0; i < 2; ++i)
        #pragma unroll
        for (int r = 0; r < 16; ++r) acc[i][r] = 0.f;

    f32x4  bA[4], bB[4];
    bf16x8 fA[4], fB[4];

    auto G_B = [&](int t, f32x4* R) {                 // t clamped: redundant ok
        if (t > 63) t = 63;
        const float* p = bSrc + (size_t)t * bStep;
        #pragma unroll
        for (int j = 0; j < 4; ++j) R[j] = *(const f32x4*)(p + j * 4);
    };
    auto G_A = [&](int t, bf16x8* F) {
        if (t > 63) t = 63;
        const char* base = aRep + (size_t)(t >> 1) * 32768 + (t & 1) * 2048 + aA0;
        F[0] = *(const bf16x8*)(base);                // i=0 ksl=0
        F[1] = *(const bf16x8*)(base + 4096);         // i=1 ksl=0
        F[2] = *(const bf16x8*)(base + 1024);         // i=0 ksl=1
        F[3] = *(const bf16x8*)(base + 4096 + 1024);  // i=1 ksl=1
    };
    auto W_B = [&](int t, const f32x4* R) {           // write LDS image for step t
        char* buf = myLds + (((t >> 1) & 1) << 12);
        const int phx = (t & 1) << 6;                 // slot g -> g+4 for odd ph
        if (is_fc) {
            bf16x8 v0, v1;
            #pragma unroll
            for (int j = 0; j < 4; ++j) {
                v0[j] = (bf16_t)R[0][j]; v0[4 + j] = (bf16_t)R[1][j];
                v1[j] = (bf16_t)R[2][j]; v1[4 + j] = (bf16_t)R[3][j];
            }
            *(bf16x8*)(buf + (fco0 ^ phx)) = v0;
            *(bf16x8*)(buf + (fco1 ^ phx)) = v1;
        } else {
            bf16x4v v0, v1, v2, v3;
            #pragma unroll
            for (int j = 0; j < 4; ++j) {
                v0[j] = (bf16_t)R[j][0]; v1[j] = (bf16_t)R[j][1];
                v2[j] = (bf16_t)R[j][2]; v3[j] = (bf16_t)R[j][3];
            }
            *(bf16x4v*)(buf + (dwo0 ^ phx)) = v0;
            *(bf16x4v*)(buf + (dwo1 ^ phx)) = v1;
            *(bf16x4v*)(buf + (dwo2 ^ phx)) = v2;
            *(bf16x4v*)(buf + (dwo3 ^ phx)) = v3;
        }
    };
    auto MM = [&](int t, const bf16x8* F) {
        const char* buf = myLds + (((t >> 1) & 1) << 12);
        const int phx = (t & 1) << 6;
        bf16x8 b0 = *(const bf16x8*)(buf + (bro0 ^ phx));
        bf16x8 b1 = *(const bf16x8*)(buf + (bro1 ^ phx));
        acc[0] = __builtin_amdgcn_mfma_f32_32x32x16_bf16(F[0], b0, acc[0], 0, 0, 0);
        acc[1] = __builtin_amdgcn_mfma_f32_32x32x16_bf16(F[1], b0, acc[1], 0, 0, 0);
        acc[0] = __builtin_amdgcn_mfma_f32_32x32x16_bf16(F[2], b1, acc[0], 0, 0, 0);
        acc[1] = __builtin_amdgcn_mfma_f32_32x32x16_bf16(F[3], b1, acc[1], 0, 0, 0);
    };

    // ---- prologue (no barriers anywhere until the epilogue) ----
    G_B(0, bA); G_B(1, bB); G_A(0, fA);
    W_B(0, bA);                     // counted vmcnt wait on bA only
    G_B(2, bA);                     // refill the freed set (2-step slack)

    // ---- main loop: 64 steps of BK=32, unrolled x2, per-wave pipeline ----
    #pragma unroll 1
    for (int s2 = 0; s2 < 32; ++s2) {
        const int s = s2 * 2;
        // even step s
        G_A(s + 1, fB);
        MM(s, fA);
        W_B(s + 1, bB);
        G_B(s + 3, bB);
        // odd step s+1
        G_A(s + 2, fA);
        MM(s + 1, fB);
        if (s2 < 31) {
            W_B(s + 2, bA);
            G_B(s + 4, bA);
        }
    }

    __syncthreads();                // waves drift: converge before LDS reuse

    // ---- epilogue (byte-identical to R11, verified) ----
    if (is_fc) {
        const int c = fcI * 32 + l31;
        if (c < 1000) {
            const float bias = fcb[c];
            #pragma unroll
            for (int i = 0; i < 2; ++i)
            #pragma unroll
            for (int r = 0; r < 16; ++r) {
                const int m = w * 64 + i * 32 + (r & 3) + 8 * (r >> 2) + 4 * half;
                out[m * 1000 + c] = acc[i][r] + bias;
            }
        }
    } else {
        float* x2 = out + 256 * 1000;
        const int n_glob = d * 32 + l31;              // = (d*8+o)*4 + h
        const float b1v = b1[n_glob], w2v = W2[n_glob];
        const float b2v = b2[n_glob >> 2];
        float* xs = (float*)lds;                      // [256 rows][8 o] = 8KB
        const int o8 = l31 >> 2;
        #pragma unroll
        for (int i = 0; i < 2; ++i)
        #pragma unroll
        for (int r = 0; r < 16; ++r) {
            float h = acc[i][r] + b1v;
            h = (h >= 0.f) ? h : 0.1f * h;            // leaky relu
            float wv = h * w2v;
            wv += __shfl_xor(wv, 1, 64);              // decoder's 4 h-cols
            wv += __shfl_xor(wv, 2, 64);
            if ((lane & 3) == 0) {
                const int row = w * 64 + i * 32 + (r & 3) + 8 * (r >> 2) + 4 * half;
                xs[row * 8 + o8] = wv + b2v;
            }
        }
        __syncthreads();
        #pragma unroll
        for (int j = 0; j < 2; ++j) {
            const int row = (tid >> 1) + j * 128, part = tid & 1;
            f32x4 v = *(const f32x4*)(xs + row * 8 + part * 4);
            *(f32x4*)(x2 + (size_t)row * 4096 + d * 8 + part * 4) = v;
        }
    }
}

extern "C" void kernel_launch(void* const* d_in, const int* in_sizes, int n_in,
                              void* d_out, int out_size, void* d_ws, size_t ws_size,
                              hipStream_t stream)
{
    (void)in_sizes; (void)n_in; (void)out_size; (void)ws_size;
    const float* x   = (const float*)d_in[0];
    const float* fcW = (const float*)d_in[1];
    const float* fcb = (const float*)d_in[2];
    const float* W1  = (const float*)d_in[3];
    const float* b1  = (const float*)d_in[4];
    const float* W2  = (const float*)d_in[5];
    const float* b2  = (const float*)d_in[6];
    char* ws = (char*)d_ws;                       // 4 MB (< proven-safe 5 MB)
    pack_a<<<128, 256, 0, stream>>>(x, ws);
    fused_dual<<<544, 256, 0, stream>>>(ws, W1, fcW, fcb, b1, W2, b2, (float*)d_out);
}

// Round 9
// 245.057 us; speedup vs baseline: 1.1180x; 1.1180x over previous
//
#include <hip/hip_runtime.h>

// DualModel3 R14: deep B prefetch ring — in-flight window > memory latency.
// R5-R13 unified post-mortem: nine schedule variants, all 84-122us, all pipes
// <15%. The one invariant: prefetch slack (load issue -> forced wait) was
// 100-600 cyc in every round, SHORTER than the 900-2000 cyc load latency.
// BW = outstanding/latency -> ~0.7-1 TB/s cap and 6-8% MfmaUtil, exactly as
// measured everywhere. Explains R13's regression (4x duplicate requests into
// the latency-limited queue) and R10 (slab loads awaited immediately).
// R14 = R12 (verified maps/epilogues/fc path/pack_a byte-identical) with ONE
// change: the decoder K-loop holds a 4-deep register ring of B superstages
// (explicit slots, literal-indexed via hand-expanded macro — no runtime
// indexing, rule #20). Iter ss: issue loads for ss+4; LDS-write ss+1 (loads
// 3 superstages ~1500-2000cyc old -> counted vmcnt ~0 wait; 12 loads in
// flight ACROSS each barrier). A reloaded JIT (single aF set) to stay <=128
// VGPR -> launch_bounds(256,4) -> 4 blocks/CU resident, 1056 blocks = 1.03
// rounds. Falsifier pre-committed: <10% gain with no spill => window theory
// dead; R15 = probe decomposition.

typedef __bf16 bf16_t;
typedef __bf16 bf16x2v __attribute__((ext_vector_type(2)));
typedef __bf16 bf16x8 __attribute__((ext_vector_type(8)));
typedef float  f32x4  __attribute__((ext_vector_type(4)));
typedef float  f32x16 __attribute__((ext_vector_type(16)));

#define WS_REP_BYTES (1 << 20)     // 1 MB per A replica, 4 replicas

__device__ __forceinline__ int bslot(int n, int g) {
    return g ^ (n & 7) ^ (((n >> 3) & 3) << 1);
}

#define BARRIER() do { \
    asm volatile("s_waitcnt lgkmcnt(0)" ::: "memory"); \
    __builtin_amdgcn_s_barrier(); \
    asm volatile("" ::: "memory"); } while (0)

// ---------------------------------------------------------------- pass 1 ----
// (byte-identical to R11/R12/R13 — verified) Frag-major A image:
// byte = rep*1MB + kt*32768 + (mchunk*256 + g*32 + lane31)*16;
// slot holds x[mchunk*32 + l][kt*64 + g*8 .. +7] as bf16x8.
__global__ __launch_bounds__(256)
void pack_a(const float* __restrict__ x, char* __restrict__ ws)
{
    const int kt  = blockIdx.x & 31;
    const int rep = blockIdx.x >> 5;                  // 0..3
    char* dst = ws + (size_t)rep * WS_REP_BYTES + (size_t)kt * 32768;
    const int tid = threadIdx.x;
    #pragma unroll
    for (int ii = 0; ii < 8; ++ii) {
        const int gi  = tid + 256 * ii;               // 0..2047
        const int mr5 = gi >> 8, g = (gi >> 5) & 7, l = gi & 31;
        const float* sp = x + (size_t)(mr5 * 32 + l) * 2048 + kt * 64 + g * 8;
        f32x4 v0 = *(const f32x4*)sp, v1 = *(const f32x4*)(sp + 4);
        bf16x8 o;
        #pragma unroll
        for (int c = 0; c < 4; ++c) { o[c] = (bf16_t)v0[c]; o[4 + c] = (bf16_t)v1[c]; }
        *(bf16x8*)(dst + gi * 16) = o;
    }
}

// ---------------------------------------------------------------- pass 2 ----
__global__ __launch_bounds__(256, 4)    // cap 128 VGPR -> 4 blk/CU (16KB LDS x4 = 64KB)
void fused_dual(const char* __restrict__ ws,
                const float* __restrict__ W1,   // [4096,2048,4] fp32
                const float* __restrict__ fcW,  // [1000,2048] fp32
                const float* __restrict__ fcb,
                const float* __restrict__ b1,
                const float* __restrict__ W2,
                const float* __restrict__ b2,
                float* __restrict__ out)        // x1[256*1000] ++ x2[256*4096]
{
    __shared__ __align__(16) char lds[2][8192];   // B superstage dbuf (2kt/half)

    const int tid  = threadIdx.x;
    const int lane = tid & 63, w = tid >> 6;      // 4 waves
    const int l31  = lane & 31, half = lane >> 5;

    // XCD swizzle: 1056 = 8 x 132, bijective (R12-verified). dec rg-siblings
    // adjacent -> duplicated W1 slab read is L2-served.
    const int idx = blockIdx.x;
    const int wid = (idx & 7) * 132 + (idx >> 3);
    const bool is_fc = (wid >= 1024);
    const int d8 = wid >> 1, rg = wid & 1;        // dec: o in [d8*8,+8), m0=rg*128
    const int fcI = wid - 1024;                   // fc: cols [fcI*32, +32)

    const char* aRep = ws + (size_t)((idx & 7) >> 1) * WS_REP_BYTES;

    // B-frag read offsets (R11/R12-verified swizzle)
    int bro[4];
    #pragma unroll
    for (int ks = 0; ks < 4; ++ks)
        bro[ks] = l31 * 128 + bslot(l31, ks * 2 + half) * 16;

    if (!is_fc) {
        // =================== decoder path: BM=128, BN=32 ===================
        const int aoff = (rg * 4 + w) * 4096 + half * 512 + l31 * 16;
        // staging map (R12-verified): o=(t>>5)&7, kg=(t>>2)&7, kp=t&3
        const int o = (tid >> 5) & 7, kg = (tid >> 2) & 7, kp = tid & 3;
        const float* bSrc = W1 + (size_t)(d8 * 8 + o) * 8192 + (kg * 8 + kp * 2) * 4;
        int dwo[4];
        #pragma unroll
        for (int h = 0; h < 4; ++h) {
            const int n = 4 * o + h;
            dwo[h] = n * 128 + bslot(n, kg) * 16 + kp * 4;
        }

        f32x16 acc;
        #pragma unroll
        for (int r = 0; r < 16; ++r) acc[r] = 0.f;

        bf16x8 aF[4];
        f32x4  bR[4][4];                // 4-slot superstage ring (literal-indexed)

        auto B_LOAD = [&](int ss, f32x4 (&R)[4]) {     // superstage = kt {2ss,2ss+1}
            const float* p = bSrc + (size_t)ss * 512;
            R[0] = *(const f32x4*)p;         R[1] = *(const f32x4*)(p + 4);
            R[2] = *(const f32x4*)(p + 256); R[3] = *(const f32x4*)(p + 260);
        };
        auto B_WRITE = [&](const f32x4 (&R)[4], char* lB) {
            #pragma unroll
            for (int ktl = 0; ktl < 2; ++ktl)
                #pragma unroll
                for (int h = 0; h < 4; ++h) {
                    bf16x2v v;
                    v[0] = (bf16_t)R[ktl * 2][h];
                    v[1] = (bf16_t)R[ktl * 2 + 1][h];
                    *(bf16x2v*)(lB + ktl * 4096 + dwo[h]) = v;
                }
        };
        auto A_PF = [&](int kt, bf16x8 (&F)[4]) {
            const char* ap = aRep + (size_t)kt * 32768 + aoff;
            #pragma unroll
            for (int ks = 0; ks < 4; ++ks)
                F[ks] = *(const bf16x8*)(ap + ks * 1024);
        };
        auto MM = [&](const bf16x8 (&F)[4], const char* lB, int ktl) {
            #pragma unroll
            for (int ks = 0; ks < 4; ++ks) {
                bf16x8 bf = *(const bf16x8*)(lB + ktl * 4096 + bro[ks]);
                acc = __builtin_amdgcn_mfma_f32_32x32x16_bf16(F[ks], bf, acc, 0, 0, 0);
            }
        };

        // prologue: fill the ring (12 loads stay in flight), seal superstage 0
        B_LOAD(0, bR[0]); B_LOAD(1, bR[1]); B_LOAD(2, bR[2]); B_LOAD(3, bR[3]);
        B_WRITE(bR[0], lds[0]);
        BARRIER();

        // iter ss: load ss+4 (slot ss&3), write ss+1 (slot (ss+1)&3, loaded
        // 3 superstages ago -> counted vmcnt ~0), compute kts {2ss,2ss+1}.
        #define DEC_STEP(ss, DOL, DOW) do { \
            if (DOL) B_LOAD((ss) + 4, bR[(ss) & 3]); \
            if (DOW) B_WRITE(bR[((ss) + 1) & 3], lds[((ss) + 1) & 1]); \
            A_PF(2 * (ss), aF); \
            MM(aF, lds[(ss) & 1], 0); \
            A_PF(2 * (ss) + 1, aF); \
            MM(aF, lds[(ss) & 1], 1); \
            BARRIER(); \
        } while (0)

        DEC_STEP(0, 1, 1);  DEC_STEP(1, 1, 1);  DEC_STEP(2, 1, 1);
        DEC_STEP(3, 1, 1);  DEC_STEP(4, 1, 1);  DEC_STEP(5, 1, 1);
        DEC_STEP(6, 1, 1);  DEC_STEP(7, 1, 1);  DEC_STEP(8, 1, 1);
        DEC_STEP(9, 1, 1);  DEC_STEP(10, 1, 1); DEC_STEP(11, 1, 1);
        DEC_STEP(12, 0, 1); DEC_STEP(13, 0, 1); DEC_STEP(14, 0, 1);
        DEC_STEP(15, 0, 0);
        #undef DEC_STEP

        // epilogue (R12-verified): C/D col=lane&31, row=(r&3)+8*(r>>2)+4*half
        float* x2 = out + 256 * 1000;
        const int n_glob = d8 * 32 + l31;
        const float b1v = b1[n_glob], w2v = W2[n_glob];
        const float b2v = b2[n_glob >> 2];
        float* xs = (float*)lds;                      // [128 rows][8 o] = 4KB
        const int o8 = l31 >> 2;
        #pragma unroll
        for (int r = 0; r < 16; ++r) {
            float h = acc[r] + b1v;
            h = (h >= 0.f) ? h : 0.1f * h;            // leaky relu
            float wv = h * w2v;
            wv += __shfl_xor(wv, 1, 64);              // decoder's 4 h-cols
            wv += __shfl_xor(wv, 2, 64);
            if ((lane & 3) == 0) {
                const int row = w * 32 + (r & 3) + 8 * (r >> 2) + 4 * half;
                xs[row * 8 + o8] = wv + b2v;
            }
        }
        __syncthreads();
        {
            const int row = tid >> 1, part = tid & 1;
            f32x4 v = *(const f32x4*)(xs + row * 8 + part * 4);
            *(f32x4*)(x2 + (size_t)(rg * 128 + row) * 4096 + d8 * 8 + part * 4) = v;
        }
    } else {
        // =================== fc path: BM=256, BN=32 (R12 verbatim) =========
        const int aoff = w * 8192 + half * 512 + l31 * 16;
        const int n = tid >> 3, kg = tid & 7;
        int c = fcI * 32 + n; if (c > 999) c = 999;   // stores guarded
        const float* bSrc = fcW + (size_t)c * 2048 + kg * 8;
        const int fcWoff = n * 128 + bslot(n, kg) * 16;

        f32x16 acc[2];
        #pragma unroll
        for (int i = 0; i < 2; ++i)
            #pragma unroll
            for (int r = 0; r < 16; ++r) acc[i][r] = 0.f;

        bf16x8 aF[8];
        f32x4  bRa[4], bRb[4];

        auto B_LOAD = [&](int ss, f32x4* R) {
            const float* p = bSrc + (size_t)ss * 128;
            R[0] = *(const f32x4*)p;        R[1] = *(const f32x4*)(p + 4);
            R[2] = *(const f32x4*)(p + 64); R[3] = *(const f32x4*)(p + 68);
        };
        auto B_WRITE = [&](const f32x4* R, char* lB) {
            #pragma unroll
            for (int ktl = 0; ktl < 2; ++ktl) {
                bf16x8 v;
                #pragma unroll
                for (int j = 0; j < 4; ++j) {
                    v[j]     = (bf16_t)R[ktl * 2][j];
                    v[4 + j] = (bf16_t)R[ktl * 2 + 1][j];
                }
                *(bf16x8*)(lB + ktl * 4096 + fcWoff) = v;
            }
        };
        auto A_PF = [&](int kt) {
            const char* ap = aRep + (size_t)kt * 32768 + aoff;
            #pragma unroll
            for (int i = 0; i < 2; ++i)
                #pragma unroll
                for (int ks = 0; ks < 4; ++ks)
                    aF[i * 4 + ks] = *(const bf16x8*)(ap + i * 4096 + ks * 1024);
        };
        auto MM = [&](const char* lB, int ktl) {
            #pragma unroll
            for (int ks = 0; ks < 4; ++ks) {
                bf16x8 bf = *(const bf16x8*)(lB + ktl * 4096 + bro[ks]);
                #pragma unroll
                for (int i = 0; i < 2; ++i)
                    acc[i] = __builtin_amdgcn_mfma_f32_32x32x16_bf16(aF[i * 4 + ks], bf, acc[i], 0, 0, 0);
            }
        };

        B_LOAD(0, bRa); B_LOAD(1, bRb);
        B_WRITE(bRa, lds[0]);
        BARRIER();

        #pragma unroll 1
        for (int ss2 = 0; ss2 < 8; ++ss2) {
            const int ss = ss2 * 2;
            {
                int sl = ss + 2; if (sl > 15) sl = 15;
                B_LOAD(sl, bRa);
                A_PF(2 * ss);     MM(lds[0], 0);
                A_PF(2 * ss + 1); MM(lds[0], 1);
                B_WRITE(bRb, lds[1]);
                BARRIER();
            }
            {
                int sl = ss + 3; if (sl > 15) sl = 15;
                B_LOAD(sl, bRb);
                A_PF(2 * ss + 2); MM(lds[1], 0);
                A_PF(2 * ss + 3); MM(lds[1], 1);
                B_WRITE(bRa, lds[0]);
                BARRIER();
            }
        }

        const int cc = fcI * 32 + l31;
        if (cc < 1000) {
            const float bias = fcb[cc];
            #pragma unroll
            for (int i = 0; i < 2; ++i)
            #pragma unroll
            for (int r = 0; r < 16; ++r) {
                const int m = w * 64 + i * 32 + (r & 3) + 8 * (r >> 2) + 4 * half;
                out[m * 1000 + cc] = acc[i][r] + bias;
            }
        }
    }
}

extern "C" void kernel_launch(void* const* d_in, const int* in_sizes, int n_in,
                              void* d_out, int out_size, void* d_ws, size_t ws_size,
                              hipStream_t stream)
{
    (void)in_sizes; (void)n_in; (void)out_size; (void)ws_size;
    const float* x   = (const float*)d_in[0];
    const float* fcW = (const float*)d_in[1];
    const float* fcb = (const float*)d_in[2];
    const float* W1  = (const float*)d_in[3];
    const float* b1  = (const float*)d_in[4];
    const float* W2  = (const float*)d_in[5];
    const float* b2  = (const float*)d_in[6];
    char* ws = (char*)d_ws;                       // 4 MB (< proven-safe 5 MB)
    pack_a<<<128, 256, 0, stream>>>(x, ws);
    fused_dual<<<1056, 256, 0, stream>>>(ws, W1, fcW, fcb, b1, W2, b2, (float*)d_out);
}